// Round 2
// baseline (104.477 us; speedup 1.0000x reference)
//
#include <hip/hip_runtime.h>

#define NROWS 8192
#define TCOLS 256
#define NBLK  256
constexpr float SIGMA_INV = 0.01f;   // 1/100

// Fused kernel. Math restructure (O(N^2) pair sum -> O(N*T)):
//   G[k]  = sum_{j: ev[j] && y[j] > k} exp(F1[j,k]/SIGMA)
//   L2    = sum_i ev[i] * exp(-A[i]/SIGMA) * G[y[i]]
//   L1    = sum_i -st[i]*log(p_at_y[i]) - (1-st[i])*log(1-A[i])
// Phase 1 (all 256 blocks): one wave per row, float4 loads, 64-lane shuffle
//   scan for the cumsum; per-block bin partials -> plain stores (no init, no
//   atomics needed; ws poison is fully overwritten).
// Phase 2 (last block to arrive, threadfence pattern): reduce partials, gather.
__global__ __launch_bounds__(256) void surv_fused(
    const float* __restrict__ yp, const int* __restrict__ y,
    const float* __restrict__ st,
    unsigned int* __restrict__ cnt,   // zeroed via 4-byte memset
    float* __restrict__ partial,      // [NBLK][256], b-major
    float* __restrict__ l1p,          // [NBLK]
    float* __restrict__ c,            // [NROWS]
    float* __restrict__ out)
{
    // Gw[wave][t][lane]: partial for bin k = lane*4 + t; lane-major -> no conflicts
    __shared__ float Gw[4][4][64];
    __shared__ float wl1[4];
    __shared__ float Gs[256];
    __shared__ float wsum[4];
    __shared__ unsigned int isLast;

    const int tid  = threadIdx.x;
    const int wave = tid >> 6;
    const int lane = tid & 63;

    Gw[wave][0][lane] = 0.f;
    Gw[wave][1][lane] = 0.f;
    Gw[wave][2][lane] = 0.f;
    Gw[wave][3][lane] = 0.f;

    float l1 = 0.f;
    const int row0 = blockIdx.x * 32;   // 256 blocks * 32 rows

    #pragma unroll 2
    for (int r = 0; r < 8; ++r) {
        const int row = row0 + wave + 4 * r;
        const float4 v =
            reinterpret_cast<const float4*>(yp + (size_t)row * TCOLS)[lane];

        // 4-elem local inclusive prefix
        const float s0 = v.x;
        const float s1 = s0 + v.y;
        const float s2 = s1 + v.z;
        const float s3 = s2 + v.w;

        // 64-lane inclusive shuffle scan of per-lane totals
        float x = s3;
        #pragma unroll
        for (int d = 1; d < 64; d <<= 1) {
            const float t = __shfl_up(x, d);
            if (lane >= d) x += t;
        }
        const float pre = x - s3;
        const float f0 = pre + s0, f1 = pre + s1, f2 = pre + s2, f3 = pre + s3;

        const int   yi  = y[row];
        const float sti = st[row];
        const bool  ev  = (sti > 0.5f);

        const int yl = yi >> 2, ye = yi & 3;
        const float fa = (ye == 0) ? f0 : (ye == 1) ? f1 : (ye == 2) ? f2 : f3;
        const float va = (ye == 0) ? v.x : (ye == 1) ? v.y : (ye == 2) ? v.z : v.w;
        const float A = __shfl(fa, yl);
        const float p = __shfl(va, yl);

        if (lane == 0) {
            l1 += -sti * __logf(p) - (1.f - sti) * __logf(1.f - A);
            c[row] = ev ? __expf(-A * SIGMA_INV) : 0.f;
        }

        if (ev) {
            const int k0 = lane << 2;
            if (k0     < yi) Gw[wave][0][lane] += __expf(f0 * SIGMA_INV);
            if (k0 + 1 < yi) Gw[wave][1][lane] += __expf(f1 * SIGMA_INV);
            if (k0 + 2 < yi) Gw[wave][2][lane] += __expf(f2 * SIGMA_INV);
            if (k0 + 3 < yi) Gw[wave][3][lane] += __expf(f3 * SIGMA_INV);
        }
    }

    if (lane == 0) wl1[wave] = l1;
    __syncthreads();

    // bin k = tid -> Gw[w][tid&3][tid>>2]; coalesced store of block partials
    const float g = Gw[0][tid & 3][tid >> 2] + Gw[1][tid & 3][tid >> 2]
                  + Gw[2][tid & 3][tid >> 2] + Gw[3][tid & 3][tid >> 2];
    partial[blockIdx.x * 256 + tid] = g;
    if (tid == 0) l1p[blockIdx.x] = wl1[0] + wl1[1] + wl1[2] + wl1[3];

    // ---- last-block-to-arrive reduction (threadfence pattern) ----
    __threadfence();                       // release our stores device-wide
    if (tid == 0) isLast = (atomicAdd(cnt, 1u) == NBLK - 1u) ? 1u : 0u;
    __syncthreads();
    if (!isLast) return;
    __threadfence();                       // acquire everyone's stores

    float s = l1p[tid];                    // fold L1 partials in (NBLK == 256)
    float gk = 0.f;
    for (int b = 0; b < NBLK; ++b)         // coalesced: consecutive tid -> consecutive k
        gk += partial[b * 256 + tid];
    Gs[tid] = gk;
    __syncthreads();

    for (int i = tid; i < NROWS; i += 256)
        s += c[i] * Gs[y[i]];

    #pragma unroll
    for (int d = 32; d; d >>= 1) s += __shfl_down(s, d);
    if ((tid & 63) == 0) wsum[tid >> 6] = s;
    __syncthreads();
    if (tid == 0) out[0] = wsum[0] + wsum[1] + wsum[2] + wsum[3];
}

extern "C" void kernel_launch(void* const* d_in, const int* in_sizes, int n_in,
                              void* d_out, int out_size, void* d_ws, size_t ws_size,
                              hipStream_t stream) {
    const float* yp = (const float*)d_in[0];   // y_pred (8192 x 256) f32
    const int*   y  = (const int*)d_in[1];     // y (8192) int
    const float* st = (const float*)d_in[2];   // status (8192) f32

    char* ws = (char*)d_ws;
    unsigned int* cnt = (unsigned int*)ws;                 // 4 B
    float* partial = (float*)(ws + 1024);                  // 256*256*4 = 256 KiB
    float* l1p     = (float*)(ws + 1024 + 262144);         // 1 KiB
    float* c       = (float*)(ws + 1024 + 262144 + 1024);  // 32 KiB
    float* out     = (float*)d_out;

    hipMemsetAsync(cnt, 0, 4, stream);     // only the arrival counter needs init
    surv_fused<<<NBLK, 256, 0, stream>>>(yp, y, st, cnt, partial, l1p, c, out);
}